// Round 1
// baseline (512.726 us; speedup 1.0000x reference)
//
#include <hip/hip_runtime.h>

// Problem constants (B=2,T=8 folded into BT)
#define BT   16
#define NN   10242
#define CC   64
#define KK   9
#define NBR_ 7
#define OO   64
#define CK   576          // C*K
#define NT   8            // nodes per block

// Transpose conv_w (O, C, 1, K) -> wt (C*K, O) so consumer loads are coalesced.
__global__ void transpose_w_kernel(const float* __restrict__ w, float* __restrict__ wt) {
    int i = blockIdx.x * blockDim.x + threadIdx.x;   // i indexes (o, q)
    if (i >= OO * CK) return;
    int o = i / CK;
    int q = i - o * CK;                              // q = c*K + k
    wt[q * OO + o] = w[i];
}

__global__ __launch_bounds__(256) void sphere_conv_kernel(
    const float* __restrict__ x,      // (BT, N, C)
    const int*   __restrict__ index,  // (N, NBR) int32
    const float* __restrict__ m,      // (N, NBR, K)
    const float* __restrict__ wt,     // (CK, O) transposed weights
    const float* __restrict__ bias,   // (O,)
    float*       __restrict__ out)    // (BT, N, O)
{
    __shared__ float itp_s[NT * CK];  // 18432 B

    const int tid = threadIdx.x;
    const int bt  = blockIdx.y;
    const int n0  = blockIdx.x * NT;
    const int c   = tid & 63;

    // ---- Producer: itp_s[ns][c*K+k] = sum_j x[bt, idx[n,j], c] * m[n,j,k] ----
    for (int ns = tid >> 6; ns < NT; ns += 4) {
        const int n = n0 + ns;
        if (n >= NN) break;                       // monotone in ns -> safe
        float acc[KK];
        #pragma unroll
        for (int k = 0; k < KK; ++k) acc[k] = 0.f;
        #pragma unroll
        for (int j = 0; j < NBR_; ++j) {
            const int idx = index[n * NBR_ + j];            // wave-uniform
            const float xv = x[(bt * NN + idx) * CC + c];   // coalesced 256B
            const float* mp = &m[(n * NBR_ + j) * KK];      // wave-uniform
            #pragma unroll
            for (int k = 0; k < KK; ++k) acc[k] = fmaf(xv, mp[k], acc[k]);
        }
        #pragma unroll
        for (int k = 0; k < KK; ++k) itp_s[ns * CK + c * KK + k] = acc[k];
    }
    __syncthreads();

    // ---- Consumer: out[bt, n, o] = sum_q itp_s[ns][q] * wt[q][o] + bias[o] ----
    const int o    = tid & 63;
    const int pair = tid >> 6;              // wave-uniform (0..3)
    const int nsA  = 2 * pair;
    const int nsB  = 2 * pair + 1;

    const float4* sA = (const float4*)&itp_s[nsA * CK];   // 2304-B aligned
    const float4* sB = (const float4*)&itp_s[nsB * CK];
    const float* wtp = wt + o;

    float acc0 = 0.f, acc1 = 0.f;
    #pragma unroll 4
    for (int q4 = 0; q4 < CK / 4; ++q4) {
        const float4 a = sA[q4];            // LDS broadcast (wave-uniform addr)
        const float4 b = sB[q4];
        const int qb = q4 * 4;
        const float w0 = wtp[(qb + 0) * OO];   // lanes o=0..63 -> 256B coalesced
        const float w1 = wtp[(qb + 1) * OO];
        const float w2 = wtp[(qb + 2) * OO];
        const float w3 = wtp[(qb + 3) * OO];
        acc0 = fmaf(a.x, w0, acc0); acc1 = fmaf(b.x, w0, acc1);
        acc0 = fmaf(a.y, w1, acc0); acc1 = fmaf(b.y, w1, acc1);
        acc0 = fmaf(a.z, w2, acc0); acc1 = fmaf(b.z, w2, acc1);
        acc0 = fmaf(a.w, w3, acc0); acc1 = fmaf(b.w, w3, acc1);
    }

    const float bo = bias[o];
    const int nA = n0 + nsA;
    const int nB = n0 + nsB;
    if (nA < NN) out[(bt * NN + nA) * OO + o] = acc0 + bo;
    if (nB < NN) out[(bt * NN + nB) * OO + o] = acc1 + bo;
}

extern "C" void kernel_launch(void* const* d_in, const int* in_sizes, int n_in,
                              void* d_out, int out_size, void* d_ws, size_t ws_size,
                              hipStream_t stream) {
    const float* x      = (const float*)d_in[0];
    const int*   index  = (const int*)  d_in[1];
    const float* m      = (const float*)d_in[2];
    const float* conv_w = (const float*)d_in[3];
    const float* conv_b = (const float*)d_in[4];
    float* out = (float*)d_out;
    float* wt  = (float*)d_ws;          // CK*OO floats = 147456 B

    // 1) transpose weights into workspace (ws is re-poisoned every call)
    {
        const int total = OO * CK;
        dim3 grid((total + 255) / 256);
        transpose_w_kernel<<<grid, 256, 0, stream>>>(conv_w, wt);
    }
    // 2) fused gather+interp+conv
    {
        dim3 grid((NN + NT - 1) / NT, BT);
        sphere_conv_kernel<<<grid, 256, 0, stream>>>(x, index, m, wt, conv_b, out);
    }
}

// Round 2
// 237.883 us; speedup vs baseline: 2.1554x; 2.1554x over previous
//
#include <hip/hip_runtime.h>

#define BT    16
#define NN    10242
#define CC    64
#define KK    9
#define NBR_  7
#define OO    64
#define CK    576
#define MT    64            // rows (nodes) per block
#define RS    584           // LDS row stride in bf16 units (576 + 8 pad -> 2-way banks)
#define KT    18            // K tiles of 32

using frag  = __attribute__((ext_vector_type(8))) short;   // 8 bf16 (4 VGPRs)
using f32x4 = __attribute__((ext_vector_type(4))) float;

static __device__ __forceinline__ unsigned short f2bf(float f) {
    union { float f; unsigned u; } v; v.f = f;
    unsigned r = v.u + 0x7fffu + ((v.u >> 16) & 1u);   // RNE
    return (unsigned short)(r >> 16);
}

// q-permutation shared by producer and weight pack:
//   k in [0,8): q = (k>>2)*256 + c*4 + (k&3)
//   k == 8   : q = 512 + c
// Pack conv_w (O, C, 1, K) into B fragments in exact MFMA register order:
//   wb[((t*4 + ct)*64 + lane)*8 + j] = bf16( w[o][c][k] )
//   where q = t*32 + (lane>>4)*8 + j,  o = ct*16 + (lane&15)
__global__ void pack_w_kernel(const float* __restrict__ w, unsigned short* __restrict__ wb) {
    int i = blockIdx.x * blockDim.x + threadIdx.x;     // 0 .. 18*4*64*8-1
    if (i >= KT * 4 * 64 * 8) return;
    int j  = i & 7;
    int l  = (i >> 3) & 63;
    int ct = (i >> 9) & 3;
    int t  = i >> 11;
    int q  = t * 32 + (l >> 4) * 8 + j;
    int o  = ct * 16 + (l & 15);
    int c, k;
    if (q < 512) { int g = q >> 8; c = (q & 255) >> 2; k = g * 4 + (q & 3); }
    else         { c = q - 512;   k = 8; }
    wb[i] = f2bf(w[(o * CC + c) * KK + k]);
}

__global__ __launch_bounds__(256) void sphere_conv_kernel(
    const float* __restrict__ x,      // (BT, N, C)
    const int*   __restrict__ index,  // (N, NBR)
    const float* __restrict__ m,      // (N, NBR, K)
    const unsigned short* __restrict__ wb,  // packed B frags (bf16 bits)
    const float* __restrict__ bias,   // (O,)
    float*       __restrict__ out)    // (BT, N, O)
{
    __shared__ unsigned short itp_s[MT * RS];   // 74752 B -> 2 blocks/CU

    const int tid  = threadIdx.x;
    const int bt   = blockIdx.x;                // bt fastest -> XCD L2 locality
    const int n0   = blockIdx.y * MT;
    const int w    = tid >> 6;                  // wave id 0..3
    const int lane = tid & 63;

    // ---------------- Producer: interp into LDS (bf16, q-permuted) ----------
    {
        const int c = lane;
        const float* xb = x + (size_t)bt * NN * CC + c;
        for (int r = 0; r < 16; ++r) {
            const int ns = w * 16 + r;
            const int n  = n0 + ns;
            if (n >= NN) break;                  // rows monotone in r
            float acc[KK];
            #pragma unroll
            for (int k = 0; k < KK; ++k) acc[k] = 0.f;
            #pragma unroll
            for (int j = 0; j < NBR_; ++j) {
                const int idx = index[n * NBR_ + j];          // wave-uniform
                const float xv = xb[(size_t)idx * CC];        // 256B coalesced
                const float* mp = &m[(n * NBR_ + j) * KK];    // wave-uniform
                #pragma unroll
                for (int k = 0; k < KK; ++k) acc[k] = fmaf(xv, mp[k], acc[k]);
            }
            unsigned short h[KK];
            #pragma unroll
            for (int k = 0; k < KK; ++k) h[k] = f2bf(acc[k]);
            // k-quad 0 -> q = c*4 + (0..3); k-quad 1 -> q = 256 + c*4 + (0..3); k=8 -> 512+c
            uint2 q0, q1;
            q0.x = (unsigned)h[0] | ((unsigned)h[1] << 16);
            q0.y = (unsigned)h[2] | ((unsigned)h[3] << 16);
            q1.x = (unsigned)h[4] | ((unsigned)h[5] << 16);
            q1.y = (unsigned)h[6] | ((unsigned)h[7] << 16);
            unsigned short* row = &itp_s[ns * RS];
            *(uint2*)(&row[c * 4])       = q0;   // 8B aligned, coalesced
            *(uint2*)(&row[256 + c * 4]) = q1;
            row[512 + c] = h[8];
        }
    }
    __syncthreads();

    // ---------------- Consumer: MFMA GEMM, wave = 16 rows x 64 cols ---------
    const int wr   = w * 16;                    // wave's row base
    const int am   = lane & 15;                 // A-frag row
    const int half = lane >> 4;                 // 0..3

    f32x4 acc[4];
    #pragma unroll
    for (int ct = 0; ct < 4; ++ct) acc[ct] = (f32x4){0.f, 0.f, 0.f, 0.f};

    const unsigned short* arow = &itp_s[(wr + am) * RS + half * 8];
    const frag* wbf = (const frag*)wb;          // [(t*4+ct)*64 + lane]

    #pragma unroll 2
    for (int t = 0; t < KT; ++t) {
        const frag a = *(const frag*)(arow + t * 32);   // ds_read_b128
        #pragma unroll
        for (int ct = 0; ct < 4; ++ct) {
            const frag b = wbf[(t * 4 + ct) * 64 + lane];
            acc[ct] = __builtin_amdgcn_mfma_f32_16x16x32_bf16(a, b, acc[ct], 0, 0, 0);
        }
    }

    // ---------------- Epilogue: bias + store ---------------------------------
    // D layout: col = lane&15, row = (lane>>4)*4 + i   [m89]
    const size_t obase = (size_t)bt * NN * OO;
    #pragma unroll
    for (int ct = 0; ct < 4; ++ct) {
        const int o  = ct * 16 + (lane & 15);
        const float bo = bias[o];
        #pragma unroll
        for (int i = 0; i < 4; ++i) {
            const int n = n0 + wr + half * 4 + i;
            if (n < NN) out[obase + (size_t)n * OO + o] = acc[ct][i] + bo;
        }
    }
}

extern "C" void kernel_launch(void* const* d_in, const int* in_sizes, int n_in,
                              void* d_out, int out_size, void* d_ws, size_t ws_size,
                              hipStream_t stream) {
    const float* x      = (const float*)d_in[0];
    const int*   index  = (const int*)  d_in[1];
    const float* m      = (const float*)d_in[2];
    const float* conv_w = (const float*)d_in[3];
    const float* conv_b = (const float*)d_in[4];
    float* out = (float*)d_out;
    unsigned short* wb = (unsigned short*)d_ws;   // 73728 B

    {   // pack weights into MFMA B-fragment order (ws re-poisoned every call)
        const int total = KT * 4 * 64 * 8;
        pack_w_kernel<<<(total + 255) / 256, 256, 0, stream>>>(conv_w, wb);
    }
    {   // fused gather + interp + MFMA conv
        dim3 grid(BT, (NN + MT - 1) / MT);        // bt fastest for XCD L2 reuse
        sphere_conv_kernel<<<grid, 256, 0, stream>>>(x, index, m, wb, conv_b, out);
    }
}

// Round 3
// 157.917 us; speedup vs baseline: 3.2468x; 1.5064x over previous
//
#include <hip/hip_runtime.h>

#define BT    16
#define NN    10242
#define CC    64
#define KK    9
#define NBR_  7
#define OO    64
#define CK    576
#define MT    32            // rows (nodes) per block
#define RS    584           // LDS row stride in bf16 units (16B-aligned rows)
#define KT    18            // K tiles of 32

using frag  = __attribute__((ext_vector_type(8))) short;   // 8 bf16 (4 VGPRs)
using f32x4 = __attribute__((ext_vector_type(4))) float;

static __device__ __forceinline__ unsigned short f2bf(float f) {
    union { float f; unsigned u; } v; v.f = f;
    unsigned r = v.u + 0x7fffu + ((v.u >> 16) & 1u);   // RNE
    return (unsigned short)(r >> 16);
}

// q-permutation shared by producer and weight pack:
//   k in [0,8): q = (k>>2)*256 + c*4 + (k&3)
//   k == 8   : q = 512 + c
// wb[((t*4 + ct)*64 + lane)*8 + j] = bf16(w[o][c][k]), q = t*32+(lane>>4)*8+j,
// o = ct*16 + (lane&15).  This kernel reads w coalesced, scatters 2B writes.
__global__ void pack_w_kernel(const float* __restrict__ w, unsigned short* __restrict__ wb) {
    int i = blockIdx.x * blockDim.x + threadIdx.x;
    if (i >= OO * CK) return;
    int o   = i / CK;
    int rem = i - o * CK;          // c*9 + k
    int c   = rem / KK;
    int k   = rem - c * KK;
    int q   = (k < 8) ? ((k >> 2) * 256 + c * 4 + (k & 3)) : (512 + c);
    int t    = q >> 5;
    int qi   = q & 31;
    int lane = (qi >> 3) * 16 + (o & 15);
    int j    = qi & 7;
    int ct   = o >> 4;
    wb[((t * 4 + ct) * 64 + lane) * 8 + j] = f2bf(w[i]);
}

__global__ __launch_bounds__(256, 4) void sphere_conv_kernel(
    const float* __restrict__ x,      // (BT, N, C)
    const int*   __restrict__ index,  // (N, NBR)
    const float* __restrict__ m,      // (N, NBR, K)
    const unsigned short* __restrict__ wb,  // packed B frags (bf16 bits)
    const float* __restrict__ bias,   // (O,)
    float*       __restrict__ out)    // (BT, N, O)
{
    __shared__ unsigned short itp_s[MT * RS];   // 37376 B -> 4 blocks/CU

    const int tid  = threadIdx.x;
    const int bt   = blockIdx.x;                // bt fastest -> XCD L2 locality
    const int n0   = blockIdx.y * MT;
    const int w    = tid >> 6;                  // wave id 0..3
    const int lane = tid & 63;

    // ---------------- Producer: 8 rows/wave, lane = channel -----------------
    {
        const float* xbt = x + (size_t)bt * NN * CC;
        #pragma unroll 2
        for (int r = 0; r < 8; ++r) {
            const int ns = w * 8 + r;
            int n  = n0 + ns;
            // clamp (reads stay in-bounds; junk rows never stored) + force
            // wave-uniform so index/m go through scalar loads (K$, bt-reused)
            int nu = __builtin_amdgcn_readfirstlane(n < NN ? n : (NN - 1));
            const int*   ip = index + nu * NBR_;          // SGPR base
            const float* mp = m + nu * (NBR_ * KK);       // SGPR base
            float acc[KK];
            #pragma unroll
            for (int k = 0; k < KK; ++k) acc[k] = 0.f;
            #pragma unroll
            for (int j = 0; j < NBR_; ++j) {
                const int idj = ip[j];                    // s_load (K$)
                const float xv = xbt[(size_t)idj * CC + lane];  // coalesced 256B
                #pragma unroll
                for (int k = 0; k < KK; ++k)
                    acc[k] = fmaf(xv, mp[j * KK + k], acc[k]);  // m: s_load
            }
            unsigned short h[KK];
            #pragma unroll
            for (int k = 0; k < KK; ++k) h[k] = f2bf(acc[k]);
            uint2 q0, q1;
            q0.x = (unsigned)h[0] | ((unsigned)h[1] << 16);
            q0.y = (unsigned)h[2] | ((unsigned)h[3] << 16);
            q1.x = (unsigned)h[4] | ((unsigned)h[5] << 16);
            q1.y = (unsigned)h[6] | ((unsigned)h[7] << 16);
            unsigned short* row = &itp_s[ns * RS];
            *(uint2*)(&row[lane * 4])       = q0;         // 8B, coalesced
            *(uint2*)(&row[256 + lane * 4]) = q1;
            row[512 + lane] = h[8];
        }
    }
    __syncthreads();

    // ------------- Consumer: wave = 16 rows x 32 cols (2 MFMA / k-tile) -----
    const int rt   = w & 1;                     // row tile
    const int cp   = w >> 1;                    // col pair
    const int am   = lane & 15;
    const int half = lane >> 4;

    f32x4 acc0 = (f32x4){0.f, 0.f, 0.f, 0.f};
    f32x4 acc1 = (f32x4){0.f, 0.f, 0.f, 0.f};

    const unsigned short* arow = &itp_s[(rt * 16 + am) * RS + half * 8];
    const frag* wbf = (const frag*)wb;

    #pragma unroll 3
    for (int t = 0; t < KT; ++t) {
        const frag a  = *(const frag*)(arow + t * 32);        // ds_read_b128
        const frag b0 = wbf[(t * 4 + 2 * cp) * 64 + lane];    // L1/L2-hot
        const frag b1 = wbf[(t * 4 + 2 * cp + 1) * 64 + lane];
        acc0 = __builtin_amdgcn_mfma_f32_16x16x32_bf16(a, b0, acc0, 0, 0, 0);
        acc1 = __builtin_amdgcn_mfma_f32_16x16x32_bf16(a, b1, acc1, 0, 0, 0);
    }

    // ---------------- Epilogue: bias + store ---------------------------------
    // D layout: col = lane&15, row = (lane>>4)*4 + i
    const size_t obase = (size_t)bt * NN * OO;
    #pragma unroll
    for (int cc = 0; cc < 2; ++cc) {
        const int o  = (2 * cp + cc) * 16 + am;
        const float bo = bias[o];
        const f32x4 a = cc ? acc1 : acc0;
        #pragma unroll
        for (int i = 0; i < 4; ++i) {
            const int n = n0 + rt * 16 + half * 4 + i;
            if (n < NN) out[obase + (size_t)n * OO + o] = a[i] + bo;
        }
    }
}

extern "C" void kernel_launch(void* const* d_in, const int* in_sizes, int n_in,
                              void* d_out, int out_size, void* d_ws, size_t ws_size,
                              hipStream_t stream) {
    const float* x      = (const float*)d_in[0];
    const int*   index  = (const int*)  d_in[1];
    const float* m      = (const float*)d_in[2];
    const float* conv_w = (const float*)d_in[3];
    const float* conv_b = (const float*)d_in[4];
    float* out = (float*)d_out;
    unsigned short* wb = (unsigned short*)d_ws;   // 73728 B

    {   // pack weights into MFMA B-fragment order (coalesced reads)
        const int total = OO * CK;
        pack_w_kernel<<<(total + 255) / 256, 256, 0, stream>>>(conv_w, wb);
    }
    {   // fused gather + interp + MFMA conv
        dim3 grid(BT, (NN + MT - 1) / MT);        // bt fastest for XCD L2 reuse
        sphere_conv_kernel<<<grid, 256, 0, stream>>>(x, index, m, wb, conv_b, out);
    }
}